// Round 1
// baseline (40.763 us; speedup 1.0000x reference)
//
#include <hip/hip_runtime.h>

#define EPSV 1e-7f

// v3: latency/occupancy-bound diagnosis (0.9 TB/s effective, ~17% VALU issue
// efficiency at 28.5us). Changes vs v2:
//  - 2 windows/thread (was 4): ~100 VGPR target (Cb 36 + X dbuf 24 + mu/iv 18
//    + 10 accs) -> 4-5 waves/SIMD instead of 2-3; 8192 waves instead of 4096.
//  - all loads are 8B-aligned float2; no havef2 branch, no per-window validity
//    predicate (wx0=510 thread is simply inactive).
//  - X rows double-buffered: ch0 loads issue before moment math, ch c+1 loads
//    issue before ch c math -> load latency hides under compute.
//  - v_rcp_f32 (__builtin_amdgcn_rcpf) replaces the IEEE divide chain.
__global__ __launch_bounds__(256, 4) void matting_loss_kernel(
    const float* __restrict__ outp, const float* __restrict__ cont,
    float* __restrict__ loss)
{
    const int H = 512, W = 512, NW = 510;
    const int HW = H * W;
    const int b  = blockIdx.z;
    const int gx = blockIdx.x * 32 + threadIdx.x;  // 0..255 -> wx0 = 2*gx in 0..510
    const int gy = blockIdx.y * 8 + threadIdx.y;   // 0..511 -> window row
    const int wx0 = gx * 2;
    const int wy  = gy;

    const float* Cin = cont + (size_t)b * 3 * HW;
    const float* Xin = outp + (size_t)b * 3 * HW;

    float contrib = 0.0f;
    const float inv9 = 1.0f / 9.0f;

    if (wy < NW && wx0 < NW) {
        const int base = wy * W + wx0;

        // Content pixels: 3 ch x 3 rows x 4 cols, two 8B-aligned float2 each.
        float Cb[3][3][4];
        #pragma unroll
        for (int ch = 0; ch < 3; ++ch)
            #pragma unroll
            for (int r = 0; r < 3; ++r) {
                const float* p = Cin + ch * HW + base + r * W;
                float2 v0 = *(const float2*)p;
                float2 v1 = *(const float2*)(p + 2);
                Cb[ch][r][0] = v0.x; Cb[ch][r][1] = v0.y;
                Cb[ch][r][2] = v1.x; Cb[ch][r][3] = v1.y;
            }

        // Prefetch channel-0 output rows; latency hides under moment math.
        float Xc[3][4];
        #pragma unroll
        for (int r = 0; r < 3; ++r) {
            const float* p = Xin + base + r * W;
            float2 v0 = *(const float2*)p;
            float2 v1 = *(const float2*)(p + 2);
            Xc[r][0] = v0.x; Xc[r][1] = v0.y; Xc[r][2] = v1.x; Xc[r][3] = v1.y;
        }

        // Per-window content moments -> mu + closed-form symmetric 3x3 inverse.
        float mu[2][3], iv[2][6];
        #pragma unroll
        for (int w = 0; w < 2; ++w) {
            float sI0 = 0, sI1 = 0, sI2 = 0;
            float s00 = 0, s01 = 0, s02 = 0, s11 = 0, s12 = 0, s22 = 0;
            #pragma unroll
            for (int r = 0; r < 3; ++r)
                #pragma unroll
                for (int c = 0; c < 3; ++c) {
                    float a = Cb[0][r][w + c], e = Cb[1][r][w + c], d = Cb[2][r][w + c];
                    sI0 += a; sI1 += e; sI2 += d;
                    s00 += a * a; s01 += a * e; s02 += a * d;
                    s11 += e * e; s12 += e * d; s22 += d * d;
                }
            float m0 = sI0 * inv9, m1 = sI1 * inv9, m2 = sI2 * inv9;
            const float ed = EPSV * inv9;
            float v00 = s00 * inv9 - m0 * m0 + ed;
            float v01 = s01 * inv9 - m0 * m1;
            float v02 = s02 * inv9 - m0 * m2;
            float v11 = s11 * inv9 - m1 * m1 + ed;
            float v12 = s12 * inv9 - m1 * m2;
            float v22 = s22 * inv9 - m2 * m2 + ed;
            float k00 = v11 * v22 - v12 * v12;
            float k01 = v02 * v12 - v01 * v22;
            float k02 = v01 * v12 - v02 * v11;
            float det = v00 * k00 + v01 * k01 + v02 * k02;
            float id  = __builtin_amdgcn_rcpf(det);   // v_rcp_f32, ~1e-7 rel err
            mu[w][0] = m0; mu[w][1] = m1; mu[w][2] = m2;
            iv[w][0] = k00 * id; iv[w][1] = k01 * id; iv[w][2] = k02 * id;
            iv[w][3] = (v00 * v22 - v02 * v02) * id;
            iv[w][4] = (v01 * v02 - v00 * v12) * id;
            iv[w][5] = (v00 * v11 - v01 * v01) * id;
        }

        // Output channels one at a time; next channel's rows prefetched
        // (double-buffer) so their latency hides under this channel's math.
        #pragma unroll
        for (int c = 0; c < 3; ++c) {
            float Xn[3][4];
            if (c < 2) {
                #pragma unroll
                for (int r = 0; r < 3; ++r) {
                    const float* p = Xin + (c + 1) * HW + base + r * W;
                    float2 v0 = *(const float2*)p;
                    float2 v1 = *(const float2*)(p + 2);
                    Xn[r][0] = v0.x; Xn[r][1] = v0.y;
                    Xn[r][2] = v1.x; Xn[r][3] = v1.y;
                }
            }
            #pragma unroll
            for (int w = 0; w < 2; ++w) {
                float S = 0, SS = 0, W0 = 0, W1 = 0, W2 = 0;
                #pragma unroll
                for (int r = 0; r < 3; ++r)
                    #pragma unroll
                    for (int cc = 0; cc < 3; ++cc) {
                        float x = Xc[r][w + cc];
                        S += x; SS += x * x;
                        W0 += x * Cb[0][r][w + cc];
                        W1 += x * Cb[1][r][w + cc];
                        W2 += x * Cb[2][r][w + cc];
                    }
                float u0 = W0 - S * mu[w][0];
                float u1 = W1 - S * mu[w][1];
                float u2 = W2 - S * mu[w][2];
                float q = u0 * (iv[w][0] * u0 + iv[w][1] * u1 + iv[w][2] * u2)
                        + u1 * (iv[w][1] * u0 + iv[w][3] * u1 + iv[w][4] * u2)
                        + u2 * (iv[w][2] * u0 + iv[w][4] * u1 + iv[w][5] * u2);
                contrib += SS - (S * S + q) * inv9;   // all windows valid by construction
            }
            if (c < 2) {
                #pragma unroll
                for (int r = 0; r < 3; ++r)
                    #pragma unroll
                    for (int j = 0; j < 4; ++j)
                        Xc[r][j] = Xn[r][j];
            }
        }
    }

    // Wave shuffle reduction -> cross-wave LDS -> one atomic per block.
    #pragma unroll
    for (int off = 32; off > 0; off >>= 1)
        contrib += __shfl_down(contrib, off, 64);

    __shared__ float wsum[4];
    const int tid = threadIdx.y * 32 + threadIdx.x;
    const int lane = tid & 63, wv = tid >> 6;
    if (lane == 0) wsum[wv] = contrib;
    __syncthreads();
    if (tid == 0)
        atomicAdd(&loss[b], wsum[0] + wsum[1] + wsum[2] + wsum[3]);
}

extern "C" void kernel_launch(void* const* d_in, const int* in_sizes, int n_in,
                              void* d_out, int out_size, void* d_ws, size_t ws_size,
                              hipStream_t stream) {
    const float* outp = (const float*)d_in[0];   // output: (4,3,512,512) f32
    const float* cont = (const float*)d_in[1];   // content: (4,3,512,512) f32
    float* loss = (float*)d_out;                 // (4,1,1) f32

    hipMemsetAsync(loss, 0, out_size * sizeof(float), stream);

    dim3 block(32, 8, 1);
    dim3 grid(8, 64, 4);   // 256 thread-cols x 512 thread-rows x 4 images
    matting_loss_kernel<<<grid, block, 0, stream>>>(outp, cont, loss);
}

// Round 2
// 29.042 us; speedup vs baseline: 1.4036x; 1.4036x over previous
//
#include <hip/hip_runtime.h>

#define EPSV 1e-7f

// v4: revert to the proven 4-window/thread structure (v2, 28.5us). v3's 2-window
// + __launch_bounds__(256,4) regressed to 40.8us -- diagnosis: min-waves pin
// forced <=128 VGPR on a ~130-reg body -> scratch spills. Changes vs v2:
//  - XCD-aware swizzle: 1024 blocks round-robin XCDs by linear id; give each
//    XCD 128 consecutive work-ids = one half-image row strip (~3.2 MB both
//    tensors) -> fits 4 MiB per-XCD L2, vertical-halo reuse becomes same-XCD
//    L2 hits instead of cross-XCD L3 misses (~600cyc -> ~200cyc).
//  - X rows double-buffered: ch0 issued before moment math, ch c+1 issued
//    before ch c's window math -> all X load latency hides under compute.
//  - v_rcp_f32 replaces IEEE divide (numerically verified in v3: passed).
__global__ __launch_bounds__(256) void matting_loss_kernel(
    const float* __restrict__ outp, const float* __restrict__ cont,
    float* __restrict__ loss)
{
    const int H = 512, W = 512, NW = 510;
    const int HW = H * W;

    // --- XCD swizzle (bijective: 1024 % 8 == 0) ---
    const int lin = blockIdx.x + 4 * (blockIdx.y + 64 * blockIdx.z);
    const int swz = (lin & 7) * 128 + (lin >> 3);
    const int b   = swz >> 8;                       // image 0..3
    const int rem = swz & 255;
    const int gx  = (rem & 3) * 32 + threadIdx.x;   // 0..127 -> wx0 = 4*gx
    const int gy  = (rem >> 2) * 8 + threadIdx.y;   // 0..511 -> window row
    const int wx0 = gx * 4;
    const int wy  = gy;

    const float* Cin = cont + (size_t)b * 3 * HW;
    const float* Xin = outp + (size_t)b * 3 * HW;

    float contrib = 0.0f;
    const float inv9 = 1.0f / 9.0f;

    if (wy < NW) {
        const bool havef2 = (wx0 + 4) < W;     // false only for gx==127
        const int base = wy * W + wx0;

        // Content pixels: 3 ch x 3 rows x 6 cols, all statically indexed.
        float Cb[3][3][6];
        #pragma unroll
        for (int ch = 0; ch < 3; ++ch)
            #pragma unroll
            for (int r = 0; r < 3; ++r) {
                const float* p = Cin + ch * HW + base + r * W;
                float4 v4 = *(const float4*)p;
                float2 v2 = havef2 ? *(const float2*)(p + 4) : make_float2(0.f, 0.f);
                Cb[ch][r][0] = v4.x; Cb[ch][r][1] = v4.y; Cb[ch][r][2] = v4.z;
                Cb[ch][r][3] = v4.w; Cb[ch][r][4] = v2.x; Cb[ch][r][5] = v2.y;
            }

        // Prefetch channel-0 output rows; latency hides under moment math.
        float Xc[3][6];
        #pragma unroll
        for (int r = 0; r < 3; ++r) {
            const float* p = Xin + base + r * W;
            float4 v4 = *(const float4*)p;
            float2 v2 = havef2 ? *(const float2*)(p + 4) : make_float2(0.f, 0.f);
            Xc[r][0] = v4.x; Xc[r][1] = v4.y; Xc[r][2] = v4.z;
            Xc[r][3] = v4.w; Xc[r][4] = v2.x; Xc[r][5] = v2.y;
        }

        // Per-window content moments -> mu + closed-form symmetric 3x3 inverse.
        float mu[4][3], iv[4][6];
        #pragma unroll
        for (int w = 0; w < 4; ++w) {
            float sI0 = 0, sI1 = 0, sI2 = 0;
            float s00 = 0, s01 = 0, s02 = 0, s11 = 0, s12 = 0, s22 = 0;
            #pragma unroll
            for (int r = 0; r < 3; ++r)
                #pragma unroll
                for (int c = 0; c < 3; ++c) {
                    float a = Cb[0][r][w + c], e = Cb[1][r][w + c], d = Cb[2][r][w + c];
                    sI0 += a; sI1 += e; sI2 += d;
                    s00 += a * a; s01 += a * e; s02 += a * d;
                    s11 += e * e; s12 += e * d; s22 += d * d;
                }
            float m0 = sI0 * inv9, m1 = sI1 * inv9, m2 = sI2 * inv9;
            const float ed = EPSV * inv9;
            float v00 = s00 * inv9 - m0 * m0 + ed;
            float v01 = s01 * inv9 - m0 * m1;
            float v02 = s02 * inv9 - m0 * m2;
            float v11 = s11 * inv9 - m1 * m1 + ed;
            float v12 = s12 * inv9 - m1 * m2;
            float v22 = s22 * inv9 - m2 * m2 + ed;
            float k00 = v11 * v22 - v12 * v12;
            float k01 = v02 * v12 - v01 * v22;
            float k02 = v01 * v12 - v02 * v11;
            float det = v00 * k00 + v01 * k01 + v02 * k02;
            float id  = __builtin_amdgcn_rcpf(det);   // v_rcp_f32
            mu[w][0] = m0; mu[w][1] = m1; mu[w][2] = m2;
            iv[w][0] = k00 * id; iv[w][1] = k01 * id; iv[w][2] = k02 * id;
            iv[w][3] = (v00 * v22 - v02 * v02) * id;
            iv[w][4] = (v01 * v02 - v00 * v12) * id;
            iv[w][5] = (v00 * v11 - v01 * v01) * id;
        }

        // Output channels one at a time; next channel's rows prefetched
        // (double-buffer) so their latency hides under this channel's math.
        #pragma unroll
        for (int c = 0; c < 3; ++c) {
            float Xn[3][6];
            if (c < 2) {
                #pragma unroll
                for (int r = 0; r < 3; ++r) {
                    const float* p = Xin + (c + 1) * HW + base + r * W;
                    float4 v4 = *(const float4*)p;
                    float2 v2 = havef2 ? *(const float2*)(p + 4) : make_float2(0.f, 0.f);
                    Xn[r][0] = v4.x; Xn[r][1] = v4.y; Xn[r][2] = v4.z;
                    Xn[r][3] = v4.w; Xn[r][4] = v2.x; Xn[r][5] = v2.y;
                }
            }
            #pragma unroll
            for (int w = 0; w < 4; ++w) {
                float S = 0, SS = 0, W0 = 0, W1 = 0, W2 = 0;
                #pragma unroll
                for (int r = 0; r < 3; ++r)
                    #pragma unroll
                    for (int cc = 0; cc < 3; ++cc) {
                        float x = Xc[r][w + cc];
                        S += x; SS += x * x;
                        W0 += x * Cb[0][r][w + cc];
                        W1 += x * Cb[1][r][w + cc];
                        W2 += x * Cb[2][r][w + cc];
                    }
                float u0 = W0 - S * mu[w][0];
                float u1 = W1 - S * mu[w][1];
                float u2 = W2 - S * mu[w][2];
                float q = u0 * (iv[w][0] * u0 + iv[w][1] * u1 + iv[w][2] * u2)
                        + u1 * (iv[w][1] * u0 + iv[w][3] * u1 + iv[w][4] * u2)
                        + u2 * (iv[w][2] * u0 + iv[w][4] * u1 + iv[w][5] * u2);
                float term = SS - (S * S + q) * inv9;
                contrib += ((wx0 + w) < NW) ? term : 0.0f;
            }
            if (c < 2) {
                #pragma unroll
                for (int r = 0; r < 3; ++r)
                    #pragma unroll
                    for (int j = 0; j < 6; ++j)
                        Xc[r][j] = Xn[r][j];
            }
        }
    }

    // Wave shuffle reduction -> cross-wave LDS -> one atomic per block.
    #pragma unroll
    for (int off = 32; off > 0; off >>= 1)
        contrib += __shfl_down(contrib, off, 64);

    __shared__ float wsum[4];
    const int tid = threadIdx.y * 32 + threadIdx.x;
    const int lane = tid & 63, wv = tid >> 6;
    if (lane == 0) wsum[wv] = contrib;
    __syncthreads();
    if (tid == 0)
        atomicAdd(&loss[b], wsum[0] + wsum[1] + wsum[2] + wsum[3]);
}

extern "C" void kernel_launch(void* const* d_in, const int* in_sizes, int n_in,
                              void* d_out, int out_size, void* d_ws, size_t ws_size,
                              hipStream_t stream) {
    const float* outp = (const float*)d_in[0];   // output: (4,3,512,512) f32
    const float* cont = (const float*)d_in[1];   // content: (4,3,512,512) f32
    float* loss = (float*)d_out;                 // (4,1,1) f32

    hipMemsetAsync(loss, 0, out_size * sizeof(float), stream);

    dim3 block(32, 8, 1);
    dim3 grid(4, 64, 4);   // 128 thread-cols x 512 thread-rows x 4 images
    matting_loss_kernel<<<grid, block, 0, stream>>>(outp, cont, loss);
}

// Round 3
// 21.220 us; speedup vs baseline: 1.9210x; 1.3686x over previous
//
#include <hip/hip_runtime.h>

#define EPSV 1e-7f

// v5: kill the atomic tail. Diagnosis: loss[0..3] share ONE cache line; all
// 1024 uniform blocks finish together and their atomicAdds serialize (~10-12us
// tail). Evidence: v3's only unexplained delta was +1024 blocks = +1024 atomics
// = +12us (40.8 measured vs 28.5) -- exact match. Fix: per-block partial to a
// private ws slot (contention-free store), tiny second kernel reduces 256
// partials/image and WRITES loss (memset dispatch dropped too).
// Main body is byte-identical to v4 to isolate the change.
__global__ __launch_bounds__(256) void matting_loss_kernel(
    const float* __restrict__ outp, const float* __restrict__ cont,
    float* __restrict__ ws)
{
    const int H = 512, W = 512, NW = 510;
    const int HW = H * W;

    // --- XCD swizzle (bijective: 1024 % 8 == 0) ---
    const int lin = blockIdx.x + 4 * (blockIdx.y + 64 * blockIdx.z);
    const int swz = (lin & 7) * 128 + (lin >> 3);
    const int b   = swz >> 8;                       // image 0..3
    const int rem = swz & 255;
    const int gx  = (rem & 3) * 32 + threadIdx.x;   // 0..127 -> wx0 = 4*gx
    const int gy  = (rem >> 2) * 8 + threadIdx.y;   // 0..511 -> window row
    const int wx0 = gx * 4;
    const int wy  = gy;

    const float* Cin = cont + (size_t)b * 3 * HW;
    const float* Xin = outp + (size_t)b * 3 * HW;

    float contrib = 0.0f;
    const float inv9 = 1.0f / 9.0f;

    if (wy < NW) {
        const bool havef2 = (wx0 + 4) < W;     // false only for gx==127
        const int base = wy * W + wx0;

        // Content pixels: 3 ch x 3 rows x 6 cols, all statically indexed.
        float Cb[3][3][6];
        #pragma unroll
        for (int ch = 0; ch < 3; ++ch)
            #pragma unroll
            for (int r = 0; r < 3; ++r) {
                const float* p = Cin + ch * HW + base + r * W;
                float4 v4 = *(const float4*)p;
                float2 v2 = havef2 ? *(const float2*)(p + 4) : make_float2(0.f, 0.f);
                Cb[ch][r][0] = v4.x; Cb[ch][r][1] = v4.y; Cb[ch][r][2] = v4.z;
                Cb[ch][r][3] = v4.w; Cb[ch][r][4] = v2.x; Cb[ch][r][5] = v2.y;
            }

        // Prefetch channel-0 output rows; latency hides under moment math.
        float Xc[3][6];
        #pragma unroll
        for (int r = 0; r < 3; ++r) {
            const float* p = Xin + base + r * W;
            float4 v4 = *(const float4*)p;
            float2 v2 = havef2 ? *(const float2*)(p + 4) : make_float2(0.f, 0.f);
            Xc[r][0] = v4.x; Xc[r][1] = v4.y; Xc[r][2] = v4.z;
            Xc[r][3] = v4.w; Xc[r][4] = v2.x; Xc[r][5] = v2.y;
        }

        // Per-window content moments -> mu + closed-form symmetric 3x3 inverse.
        float mu[4][3], iv[4][6];
        #pragma unroll
        for (int w = 0; w < 4; ++w) {
            float sI0 = 0, sI1 = 0, sI2 = 0;
            float s00 = 0, s01 = 0, s02 = 0, s11 = 0, s12 = 0, s22 = 0;
            #pragma unroll
            for (int r = 0; r < 3; ++r)
                #pragma unroll
                for (int c = 0; c < 3; ++c) {
                    float a = Cb[0][r][w + c], e = Cb[1][r][w + c], d = Cb[2][r][w + c];
                    sI0 += a; sI1 += e; sI2 += d;
                    s00 += a * a; s01 += a * e; s02 += a * d;
                    s11 += e * e; s12 += e * d; s22 += d * d;
                }
            float m0 = sI0 * inv9, m1 = sI1 * inv9, m2 = sI2 * inv9;
            const float ed = EPSV * inv9;
            float v00 = s00 * inv9 - m0 * m0 + ed;
            float v01 = s01 * inv9 - m0 * m1;
            float v02 = s02 * inv9 - m0 * m2;
            float v11 = s11 * inv9 - m1 * m1 + ed;
            float v12 = s12 * inv9 - m1 * m2;
            float v22 = s22 * inv9 - m2 * m2 + ed;
            float k00 = v11 * v22 - v12 * v12;
            float k01 = v02 * v12 - v01 * v22;
            float k02 = v01 * v12 - v02 * v11;
            float det = v00 * k00 + v01 * k01 + v02 * k02;
            float id  = __builtin_amdgcn_rcpf(det);   // v_rcp_f32
            mu[w][0] = m0; mu[w][1] = m1; mu[w][2] = m2;
            iv[w][0] = k00 * id; iv[w][1] = k01 * id; iv[w][2] = k02 * id;
            iv[w][3] = (v00 * v22 - v02 * v02) * id;
            iv[w][4] = (v01 * v02 - v00 * v12) * id;
            iv[w][5] = (v00 * v11 - v01 * v01) * id;
        }

        // Output channels one at a time; next channel's rows prefetched
        // (double-buffer) so their latency hides under this channel's math.
        #pragma unroll
        for (int c = 0; c < 3; ++c) {
            float Xn[3][6];
            if (c < 2) {
                #pragma unroll
                for (int r = 0; r < 3; ++r) {
                    const float* p = Xin + (c + 1) * HW + base + r * W;
                    float4 v4 = *(const float4*)p;
                    float2 v2 = havef2 ? *(const float2*)(p + 4) : make_float2(0.f, 0.f);
                    Xn[r][0] = v4.x; Xn[r][1] = v4.y; Xn[r][2] = v4.z;
                    Xn[r][3] = v4.w; Xn[r][4] = v2.x; Xn[r][5] = v2.y;
                }
            }
            #pragma unroll
            for (int w = 0; w < 4; ++w) {
                float S = 0, SS = 0, W0 = 0, W1 = 0, W2 = 0;
                #pragma unroll
                for (int r = 0; r < 3; ++r)
                    #pragma unroll
                    for (int cc = 0; cc < 3; ++cc) {
                        float x = Xc[r][w + cc];
                        S += x; SS += x * x;
                        W0 += x * Cb[0][r][w + cc];
                        W1 += x * Cb[1][r][w + cc];
                        W2 += x * Cb[2][r][w + cc];
                    }
                float u0 = W0 - S * mu[w][0];
                float u1 = W1 - S * mu[w][1];
                float u2 = W2 - S * mu[w][2];
                float q = u0 * (iv[w][0] * u0 + iv[w][1] * u1 + iv[w][2] * u2)
                        + u1 * (iv[w][1] * u0 + iv[w][3] * u1 + iv[w][4] * u2)
                        + u2 * (iv[w][2] * u0 + iv[w][4] * u1 + iv[w][5] * u2);
                float term = SS - (S * S + q) * inv9;
                contrib += ((wx0 + w) < NW) ? term : 0.0f;
            }
            if (c < 2) {
                #pragma unroll
                for (int r = 0; r < 3; ++r)
                    #pragma unroll
                    for (int j = 0; j < 6; ++j)
                        Xc[r][j] = Xn[r][j];
            }
        }
    }

    // Wave shuffle reduction -> cross-wave LDS -> ONE plain store per block
    // (contention-free; no atomics anywhere).
    #pragma unroll
    for (int off = 32; off > 0; off >>= 1)
        contrib += __shfl_down(contrib, off, 64);

    __shared__ float wsum[4];
    const int tid = threadIdx.y * 32 + threadIdx.x;
    const int lane = tid & 63, wv = tid >> 6;
    if (lane == 0) wsum[wv] = contrib;
    __syncthreads();
    if (tid == 0)
        ws[swz] = wsum[0] + wsum[1] + wsum[2] + wsum[3];
}

// Tiny reducer: image b owns ws[b*256 .. b*256+255] (swz>>8 == b). Writes
// loss[b] directly -- no memset dispatch needed.
__global__ __launch_bounds__(256) void reduce_kernel(
    const float* __restrict__ ws, float* __restrict__ loss)
{
    const int b = blockIdx.x;
    const int t = threadIdx.x;
    float v = ws[b * 256 + t];
    #pragma unroll
    for (int off = 32; off > 0; off >>= 1)
        v += __shfl_down(v, off, 64);

    __shared__ float s[4];
    if ((t & 63) == 0) s[t >> 6] = v;
    __syncthreads();
    if (t == 0) loss[b] = s[0] + s[1] + s[2] + s[3];
}

extern "C" void kernel_launch(void* const* d_in, const int* in_sizes, int n_in,
                              void* d_out, int out_size, void* d_ws, size_t ws_size,
                              hipStream_t stream) {
    const float* outp = (const float*)d_in[0];   // output: (4,3,512,512) f32
    const float* cont = (const float*)d_in[1];   // content: (4,3,512,512) f32
    float* loss = (float*)d_out;                 // (4,1,1) f32
    float* ws   = (float*)d_ws;                  // 1024 floats of workspace

    dim3 block(32, 8, 1);
    dim3 grid(4, 64, 4);   // 128 thread-cols x 512 thread-rows x 4 images
    matting_loss_kernel<<<grid, block, 0, stream>>>(outp, cont, ws);
    reduce_kernel<<<dim3(4, 1, 1), dim3(256, 1, 1), 0, stream>>>(ws, loss);
}

// Round 4
// 17.647 us; speedup vs baseline: 2.3098x; 1.2024x over previous
//
#include <hip/hip_runtime.h>

#define EPSV 1e-7f

// v6: instruction diet via column-sum factorization (discriminates issue-bound
// vs latency-bound). The 4 windows/thread share 6 pixel columns; compute
// per-column partial sums ONCE (9 moment quantities, 5 X quantities), then
// each window sums 3 adjacent columns. ~-15-20% VALU insts vs v5. X dbuf
// dropped (proven neutral, -18 VGPR, -36 movs). Kept: XCD swizzle, v_rcp_f32,
// ch0 X hoist, contention-free two-kernel reduction (v5's win: serialized
// same-line atomics cost ~8-10us; 1024 plain stores + tiny reducer instead).
// Pre-committed read: ~18.5-19us => issue-bound, continue inst diet;
// neutral => latency-bound, LDS staging next.
__global__ __launch_bounds__(256) void matting_loss_kernel(
    const float* __restrict__ outp, const float* __restrict__ cont,
    float* __restrict__ ws)
{
    const int H = 512, W = 512, NW = 510;
    const int HW = H * W;

    // --- XCD swizzle (bijective: 1024 % 8 == 0) ---
    const int lin = blockIdx.x + 4 * (blockIdx.y + 64 * blockIdx.z);
    const int swz = (lin & 7) * 128 + (lin >> 3);
    const int b   = swz >> 8;                       // image 0..3
    const int rem = swz & 255;
    const int gx  = (rem & 3) * 32 + threadIdx.x;   // 0..127 -> wx0 = 4*gx
    const int gy  = (rem >> 2) * 8 + threadIdx.y;   // 0..511 -> window row
    const int wx0 = gx * 4;
    const int wy  = gy;

    const float* Cin = cont + (size_t)b * 3 * HW;
    const float* Xin = outp + (size_t)b * 3 * HW;

    float contrib = 0.0f;
    const float inv9 = 1.0f / 9.0f;

    if (wy < NW) {
        const bool havef2 = (wx0 + 4) < W;     // false only for gx==127
        const int base = wy * W + wx0;

        // Content pixels: 3 ch x 3 rows x 6 cols.
        float Cb[3][3][6];
        #pragma unroll
        for (int ch = 0; ch < 3; ++ch)
            #pragma unroll
            for (int r = 0; r < 3; ++r) {
                const float* p = Cin + ch * HW + base + r * W;
                float4 v4 = *(const float4*)p;
                float2 v2 = havef2 ? *(const float2*)(p + 4) : make_float2(0.f, 0.f);
                Cb[ch][r][0] = v4.x; Cb[ch][r][1] = v4.y; Cb[ch][r][2] = v4.z;
                Cb[ch][r][3] = v4.w; Cb[ch][r][4] = v2.x; Cb[ch][r][5] = v2.y;
            }

        // Hoist channel-0 X rows; latency hides under the moment phase.
        float Xc[3][6];
        #pragma unroll
        for (int r = 0; r < 3; ++r) {
            const float* p = Xin + base + r * W;
            float4 v4 = *(const float4*)p;
            float2 v2 = havef2 ? *(const float2*)(p + 4) : make_float2(0.f, 0.f);
            Xc[r][0] = v4.x; Xc[r][1] = v4.y; Xc[r][2] = v4.z;
            Xc[r][3] = v4.w; Xc[r][4] = v2.x; Xc[r][5] = v2.y;
        }

        // --- Moment phase: per-column partial sums (computed once) ---
        float cI0[6], cI1[6], cI2[6];
        float c00[6], c01[6], c02[6], c11[6], c12[6], c22[6];
        #pragma unroll
        for (int j = 0; j < 6; ++j) {
            float a0 = Cb[0][0][j], a1 = Cb[0][1][j], a2 = Cb[0][2][j];
            float e0 = Cb[1][0][j], e1 = Cb[1][1][j], e2 = Cb[1][2][j];
            float d0 = Cb[2][0][j], d1 = Cb[2][1][j], d2 = Cb[2][2][j];
            cI0[j] = a0 + a1 + a2;
            cI1[j] = e0 + e1 + e2;
            cI2[j] = d0 + d1 + d2;
            c00[j] = a0 * a0 + a1 * a1 + a2 * a2;
            c01[j] = a0 * e0 + a1 * e1 + a2 * e2;
            c02[j] = a0 * d0 + a1 * d1 + a2 * d2;
            c11[j] = e0 * e0 + e1 * e1 + e2 * e2;
            c12[j] = e0 * d0 + e1 * d1 + e2 * d2;
            c22[j] = d0 * d0 + d1 * d1 + d2 * d2;
        }

        // Per-window: 3-column sums -> mu + closed-form symmetric 3x3 inverse.
        float mu[4][3], iv[4][6];
        #pragma unroll
        for (int w = 0; w < 4; ++w) {
            float sI0 = cI0[w] + cI0[w + 1] + cI0[w + 2];
            float sI1 = cI1[w] + cI1[w + 1] + cI1[w + 2];
            float sI2 = cI2[w] + cI2[w + 1] + cI2[w + 2];
            float s00 = c00[w] + c00[w + 1] + c00[w + 2];
            float s01 = c01[w] + c01[w + 1] + c01[w + 2];
            float s02 = c02[w] + c02[w + 1] + c02[w + 2];
            float s11 = c11[w] + c11[w + 1] + c11[w + 2];
            float s12 = c12[w] + c12[w + 1] + c12[w + 2];
            float s22 = c22[w] + c22[w + 1] + c22[w + 2];
            float m0 = sI0 * inv9, m1 = sI1 * inv9, m2 = sI2 * inv9;
            const float ed = EPSV * inv9;
            float v00 = s00 * inv9 - m0 * m0 + ed;
            float v01 = s01 * inv9 - m0 * m1;
            float v02 = s02 * inv9 - m0 * m2;
            float v11 = s11 * inv9 - m1 * m1 + ed;
            float v12 = s12 * inv9 - m1 * m2;
            float v22 = s22 * inv9 - m2 * m2 + ed;
            float k00 = v11 * v22 - v12 * v12;
            float k01 = v02 * v12 - v01 * v22;
            float k02 = v01 * v12 - v02 * v11;
            float det = v00 * k00 + v01 * k01 + v02 * k02;
            float id  = __builtin_amdgcn_rcpf(det);   // v_rcp_f32
            mu[w][0] = m0; mu[w][1] = m1; mu[w][2] = m2;
            iv[w][0] = k00 * id; iv[w][1] = k01 * id; iv[w][2] = k02 * id;
            iv[w][3] = (v00 * v22 - v02 * v02) * id;
            iv[w][4] = (v01 * v02 - v00 * v12) * id;
            iv[w][5] = (v00 * v11 - v01 * v01) * id;
        }

        // --- X phase: per-column partials distributed into window accums ---
        #pragma unroll
        for (int c = 0; c < 3; ++c) {
            if (c > 0) {
                #pragma unroll
                for (int r = 0; r < 3; ++r) {
                    const float* p = Xin + c * HW + base + r * W;
                    float4 v4 = *(const float4*)p;
                    float2 v2 = havef2 ? *(const float2*)(p + 4) : make_float2(0.f, 0.f);
                    Xc[r][0] = v4.x; Xc[r][1] = v4.y; Xc[r][2] = v4.z;
                    Xc[r][3] = v4.w; Xc[r][4] = v2.x; Xc[r][5] = v2.y;
                }
            }
            float S[4]  = {0, 0, 0, 0};
            float SS[4] = {0, 0, 0, 0};
            float W0[4] = {0, 0, 0, 0};
            float W1[4] = {0, 0, 0, 0};
            float W2[4] = {0, 0, 0, 0};
            #pragma unroll
            for (int j = 0; j < 6; ++j) {
                float x0 = Xc[0][j], x1 = Xc[1][j], x2 = Xc[2][j];
                float cS  = x0 + x1 + x2;
                float cSS = x0 * x0 + x1 * x1 + x2 * x2;
                float cW0 = x0 * Cb[0][0][j] + x1 * Cb[0][1][j] + x2 * Cb[0][2][j];
                float cW1 = x0 * Cb[1][0][j] + x1 * Cb[1][1][j] + x2 * Cb[1][2][j];
                float cW2 = x0 * Cb[2][0][j] + x1 * Cb[2][1][j] + x2 * Cb[2][2][j];
                #pragma unroll
                for (int w = 0; w < 4; ++w)
                    if (w <= j && j <= w + 2) {   // compile-time predicate
                        S[w] += cS; SS[w] += cSS;
                        W0[w] += cW0; W1[w] += cW1; W2[w] += cW2;
                    }
            }
            #pragma unroll
            for (int w = 0; w < 4; ++w) {
                float u0 = W0[w] - S[w] * mu[w][0];
                float u1 = W1[w] - S[w] * mu[w][1];
                float u2 = W2[w] - S[w] * mu[w][2];
                float q = u0 * (iv[w][0] * u0 + iv[w][1] * u1 + iv[w][2] * u2)
                        + u1 * (iv[w][1] * u0 + iv[w][3] * u1 + iv[w][4] * u2)
                        + u2 * (iv[w][2] * u0 + iv[w][4] * u1 + iv[w][5] * u2);
                float term = SS[w] - (S[w] * S[w] + q) * inv9;
                contrib += ((wx0 + w) < NW) ? term : 0.0f;
            }
        }
    }

    // Wave shuffle reduction -> cross-wave LDS -> ONE plain store per block.
    #pragma unroll
    for (int off = 32; off > 0; off >>= 1)
        contrib += __shfl_down(contrib, off, 64);

    __shared__ float wsum[4];
    const int tid = threadIdx.y * 32 + threadIdx.x;
    const int lane = tid & 63, wv = tid >> 6;
    if (lane == 0) wsum[wv] = contrib;
    __syncthreads();
    if (tid == 0)
        ws[swz] = wsum[0] + wsum[1] + wsum[2] + wsum[3];
}

// Tiny reducer: image b owns ws[b*256 .. b*256+255]. Writes loss[b] directly.
__global__ __launch_bounds__(256) void reduce_kernel(
    const float* __restrict__ ws, float* __restrict__ loss)
{
    const int b = blockIdx.x;
    const int t = threadIdx.x;
    float v = ws[b * 256 + t];
    #pragma unroll
    for (int off = 32; off > 0; off >>= 1)
        v += __shfl_down(v, off, 64);

    __shared__ float s[4];
    if ((t & 63) == 0) s[t >> 6] = v;
    __syncthreads();
    if (t == 0) loss[b] = s[0] + s[1] + s[2] + s[3];
}

extern "C" void kernel_launch(void* const* d_in, const int* in_sizes, int n_in,
                              void* d_out, int out_size, void* d_ws, size_t ws_size,
                              hipStream_t stream) {
    const float* outp = (const float*)d_in[0];   // output: (4,3,512,512) f32
    const float* cont = (const float*)d_in[1];   // content: (4,3,512,512) f32
    float* loss = (float*)d_out;                 // (4,1,1) f32
    float* ws   = (float*)d_ws;                  // 1024 floats of workspace

    dim3 block(32, 8, 1);
    dim3 grid(4, 64, 4);   // 128 thread-cols x 512 thread-rows x 4 images
    matting_loss_kernel<<<grid, block, 0, stream>>>(outp, cont, ws);
    reduce_kernel<<<dim3(4, 1, 1), dim3(256, 1, 1), 0, stream>>>(ws, loss);
}